// Round 9
// baseline (213.852 us; speedup 1.0000x reference)
//
#include <hip/hip_runtime.h>
#include <stdint.h>

#define DMAX 80
#define BLK  256
#define XW   96          // padded row stride of xsel (>= m+1)
#define GRID 2048        // expand grid: long-lived blocks, fill-like window

typedef float f32x4 __attribute__((ext_vector_type(4)));

// ---------------------------------------------------------------------------
// Setup: mask detect + compact idx; pairtab (u16 i|j<<8); coltab base copy
// plus 3 shifted copies (copy s at coltab[s*tpad + (c-s)] holds entry c) so
// a 16B-aligned uint4 load exists for any column phase.
//   column c = pps[p] * xsel[k]; entry = p | k<<16
//     [0,m)      order-1: p=P (sentinel pps=1), k=c
//     [m, m+P)   order-2: p=rank,               k=m (sentinel x=1)
//     [m+P, T)   order-3: run over k in [j,m) per pair (i,j)
// ---------------------------------------------------------------------------
__global__ void maskde_setup(const void* __restrict__ mask_raw, int m,
                             int* __restrict__ idx_out,
                             uint16_t* __restrict__ pair16,
                             uint32_t* __restrict__ coltab,
                             int tpad, int T, int P) {
    int tid = blockIdx.x * blockDim.x + threadIdx.x;

    if (tid == 0) {
        const uint8_t* b8  = (const uint8_t*)mask_raw;
        const int*     b32 = (const int*)mask_raw;
        const float*   bf  = (const float*)mask_raw;
        int cnt = 0; bool ok = true;
        for (int i = 0; i < DMAX; ++i) { uint8_t v = b8[i]; if (v > 1) ok = false; cnt += (v != 0); }
        int mode;
        if (ok && cnt == m) {
            mode = 0;
        } else {
            cnt = 0; ok = true;
            for (int i = 0; i < DMAX; ++i) { int v = b32[i]; if (v != 0 && v != 1) ok = false; cnt += (v != 0); }
            mode = (ok && cnt == m) ? 1 : 2;
        }
        int k = 0;
        for (int i = 0; i < DMAX && k < m; ++i) {
            bool on = (mode == 0) ? (b8[i] != 0)
                    : (mode == 1) ? (b32[i] != 0)
                                  : (bf[i] != 0.0f);
            if (on) idx_out[k++] = i;
        }
    }

    int stride = gridDim.x * blockDim.x;
    for (int p = tid; p < P; p += stride) {
        int rem = p, i = 0;
        while (rem >= m - i) { rem -= (m - i); ++i; }
        int j = i + rem;

        pair16[p] = (uint16_t)(i | (j << 8));

        #define WR4(c, v) do {                                              \
            int _c = (c); uint32_t _v = (v);                                \
            coltab[_c] = _v;                                                \
            if (_c >= 1) coltab[tpad     + _c - 1] = _v;                    \
            if (_c >= 2) coltab[2 * tpad + _c - 2] = _v;                    \
            if (_c >= 3) coltab[3 * tpad + _c - 3] = _v;                    \
        } while (0)

        if (p < m)
            WR4(p, (uint32_t)P | ((uint32_t)p << 16));        // order-1
        WR4(m + p, (uint32_t)p | ((uint32_t)m << 16));        // order-2

        int mi = m - i;
        long long Si  = ((long long)m * (m + 1) * (m + 2)
                       - (long long)mi * (mi + 1) * (mi + 2)) / 6;
        int Rij = ((m - i) + (m - j + 1)) * (j - i) / 2;
        int base = m + P + (int)Si + Rij;
        for (int k3 = j; k3 < m; ++k3)
            WR4(base + (k3 - j), (uint32_t)p | ((uint32_t)k3 << 16));
        #undef WR4
    }
}

// ---------------------------------------------------------------------------
// xsel[row*XW + k] = x[row*80 + idx[k]] for k<m, 1.0 for k>=m (sentinel).
// ---------------------------------------------------------------------------
__global__ void maskde_xsel(const float* __restrict__ x,
                            const int* __restrict__ idx,
                            float* __restrict__ xsel, int m, int rows) {
    int g = blockIdx.x * BLK + threadIdx.x;
    int total = rows * XW;
    for (; g < total; g += gridDim.x * BLK) {
        int row = g / XW, k = g - row * XW;
        xsel[g] = (k < m) ? x[row * DMAX + idx[k]] : 1.0f;
    }
}

// ---------------------------------------------------------------------------
// pps_all[row*PPS + p] = xsel_i * xsel_j  (p<P), 1.0 at p=P (sentinel).
// grid = (ceil(PPS/BLK), rows); coalesced row-major write (~31 MB).
// ---------------------------------------------------------------------------
__global__ void maskde_ppsall(const float* __restrict__ xsel,
                              const uint16_t* __restrict__ pair16,
                              float* __restrict__ ppsall,
                              int P, int PPS) {
    int p   = blockIdx.x * BLK + threadIdx.x;
    int row = blockIdx.y;
    if (p > P) return;
    float v = 1.0f;
    if (p < P) {
        uint32_t ij = pair16[p];
        const float* xr = xsel + row * XW;
        v = xr[ij & 0xFF] * xr[(ij >> 8) & 0xFF];
    }
    ppsall[(size_t)row * PPS + p] = v;
}

// ---------------------------------------------------------------------------
// Expand, GRID-STRIDE FILL-ISOMORPHIC: no LDS, no barriers, no prologue.
// Thread handles flat quad e=4*q; all blocks sweep one compact sliding
// window exactly like the fill kernel.  Per quad: 1 aligned uint4 table
// load + 4 pps + 4 xsel dword loads (L2-hot) + 1 aligned float4 store.
// row = e/T via 2^40 magic-mul with +-1 fixup; row-crossing quads scalar.
// ---------------------------------------------------------------------------
__global__ __launch_bounds__(BLK) void
maskde_expand(const float* __restrict__ xsel,
              const float* __restrict__ ppsall,
              const uint32_t* __restrict__ coltab, int tpad,
              float* __restrict__ out, int T, int PPS,
              int total, unsigned long long magicM) {
    const int nquads = total >> 2;
    const int gsz    = (int)gridDim.x * BLK;

    for (int q = blockIdx.x * BLK + threadIdx.x; q < nquads; q += gsz) {
        int e = q << 2;
        int row = (int)(((unsigned long long)e * magicM) >> 40);
        int c = e - row * T;
        if (c < 0)       { --row; c += T; }
        else if (c >= T) { ++row; c -= T; }

        const float* pr = ppsall + (size_t)row * PPS;
        const float* xr = xsel + row * XW;

        if (c <= T - 4) {
            int s = c & 3;
            uint4 t = *(const uint4*)(coltab + (size_t)s * tpad + (c - s));
            f32x4 o;
            o.x = pr[t.x & 0xFFFF] * xr[t.x >> 16];
            o.y = pr[t.y & 0xFFFF] * xr[t.y >> 16];
            o.z = pr[t.z & 0xFFFF] * xr[t.z >> 16];
            o.w = pr[t.w & 0xFFFF] * xr[t.w >> 16];
            *(f32x4*)(out + e) = o;     // e % 4 == 0 -> 16B aligned
        } else {
            // row-crossing quad (rare): scalar
            for (int u = 0; u < 4; ++u) {
                int e2 = e + u;
                if (e2 >= total) break;
                int c2 = e2 - row * T;
                const float* p2 = pr;
                const float* x2 = xr;
                if (c2 >= T) {
                    c2 -= T;
                    p2 = ppsall + (size_t)(row + 1) * PPS;
                    x2 = xsel + (row + 1) * XW;
                }
                uint32_t en = coltab[c2];
                out[e2] = p2[en & 0xFFFF] * x2[en >> 16];
            }
        }
    }
}

extern "C" void kernel_launch(void* const* d_in, const int* in_sizes, int n_in,
                              void* d_out, int out_size, void* d_ws, size_t ws_size,
                              hipStream_t stream) {
    const float* x    = (const float*)d_in[0];
    const void*  mask = d_in[1];
    float*       out  = (float*)d_out;

    int rows = in_sizes[0] / DMAX;
    if (rows <= 0 || out_size <= 0) return;
    long long Tll = (long long)out_size / rows;

    // recover m from T(m) = m + m(m+1)/2 + m(m+1)(m+2)/6
    int m = -1;
    for (int mm = 0; mm <= DMAX; ++mm) {
        long long t = (long long)mm
                    + (long long)mm * (mm + 1) / 2
                    + (long long)mm * (mm + 1) * (mm + 2) / 6;
        if (t == Tll) { m = mm; break; }
    }
    if (m <= 0) return;

    int T     = (int)Tll;
    int P     = m * (m + 1) / 2;
    int PPS   = P + 1;
    int tpad  = (T + 3) & ~3;
    int total = rows * T;
    unsigned long long magicM = (1ULL << 40) / (unsigned long long)T + 1;

    // workspace layout (all 256B-aligned regions)
    char* ws = (char*)d_ws;
    int*      idx    = (int*)ws;                                  // 512 B
    uint16_t* pair16 = (uint16_t*)(ws + 1024);                    // 2P B
    uint32_t* coltab = (uint32_t*)(ws + 32768);                   // 4*tpad u32
    size_t off_xsel  = 32768 + (size_t)4 * tpad * 4 + 256;
    off_xsel = (off_xsel + 255) & ~(size_t)255;
    float*    xsel   = (float*)(ws + off_xsel);                   // rows*XW f32
    size_t off_pps   = off_xsel + (size_t)rows * XW * 4;
    off_pps = (off_pps + 255) & ~(size_t)255;
    float*    ppsall = (float*)(ws + off_pps);                    // rows*PPS f32

    int sblocks = (P + 255) / 256;
    if (sblocks < 1) sblocks = 1;
    maskde_setup<<<sblocks, 256, 0, stream>>>(mask, m, idx, pair16, coltab,
                                              tpad, T, P);

    int xblocks = (rows * XW + BLK - 1) / BLK;
    if (xblocks > 2048) xblocks = 2048;
    maskde_xsel<<<xblocks, BLK, 0, stream>>>(x, idx, xsel, m, rows);

    dim3 pgrid((PPS + BLK - 1) / BLK, rows);
    maskde_ppsall<<<pgrid, BLK, 0, stream>>>(xsel, pair16, ppsall, P, PPS);

    maskde_expand<<<GRID, BLK, 0, stream>>>(xsel, ppsall, coltab, tpad,
                                            out, T, PPS, total, magicM);
}

// Round 10
// 140.625 us; speedup vs baseline: 1.5207x; 1.5207x over previous
//
#include <hip/hip_runtime.h>
#include <stdint.h>

#define DMAX   80
#define BLK    256
#define XW     96      // xsel row stride (global, >= m+1)
#define XL     64      // xls row stride in LDS (u16 path: k < 64)
#define EPBMAX 16384   // output elements per block (64 KB)
#define NR     3       // max rows staged per block (EPB <= 2T guaranteed)

typedef float f32x4 __attribute__((ext_vector_type(4)));

// ---------------------------------------------------------------------------
// Setup: mask detect + compact idx; pair16 (i|j<<8); column table with 3
// shifted copies (copy s at tab[s*tpad + (c-s)]) so any column phase has an
// 8B/16B-aligned vector load.  Entry: u16 p|k<<10 (if P<1024 && m<63) else
// u32 p|k<<16.  column c = pps[p] * xsel[k]:
//   [0,m)      order-1: p=P (sentinel pps=1), k=c
//   [m, m+P)   order-2: p=rank,               k=m (sentinel xsel=1)
//   [m+P, T)   order-3: run over k in [j,m) per pair (i,j)
// ---------------------------------------------------------------------------
__global__ void maskde_setup(const void* __restrict__ mask_raw, int m,
                             int* __restrict__ idx_out,
                             uint16_t* __restrict__ pair16,
                             uint16_t* __restrict__ tab16,
                             uint32_t* __restrict__ tab32,
                             int use16, int tpad, int T, int P) {
    int tid = blockIdx.x * blockDim.x + threadIdx.x;

    if (tid == 0) {
        const uint8_t* b8  = (const uint8_t*)mask_raw;
        const int*     b32 = (const int*)mask_raw;
        const float*   bf  = (const float*)mask_raw;
        int cnt = 0; bool ok = true;
        for (int i = 0; i < DMAX; ++i) { uint8_t v = b8[i]; if (v > 1) ok = false; cnt += (v != 0); }
        int mode;
        if (ok && cnt == m) {
            mode = 0;
        } else {
            cnt = 0; ok = true;
            for (int i = 0; i < DMAX; ++i) { int v = b32[i]; if (v != 0 && v != 1) ok = false; cnt += (v != 0); }
            mode = (ok && cnt == m) ? 1 : 2;
        }
        int k = 0;
        for (int i = 0; i < DMAX && k < m; ++i) {
            bool on = (mode == 0) ? (b8[i] != 0)
                    : (mode == 1) ? (b32[i] != 0)
                                  : (bf[i] != 0.0f);
            if (on) idx_out[k++] = i;
        }
    }

    int stride = gridDim.x * blockDim.x;
    for (int p = tid; p < P; p += stride) {
        int rem = p, i = 0;
        while (rem >= m - i) { rem -= (m - i); ++i; }
        int j = i + rem;

        pair16[p] = (uint16_t)(i | (j << 8));

        #define WR4(c, pf, kf) do {                                          \
            int _c = (c);                                                    \
            if (use16) {                                                     \
                uint16_t _v = (uint16_t)((pf) | ((kf) << 10));               \
                tab16[_c] = _v;                                              \
                if (_c >= 1) tab16[tpad     + _c - 1] = _v;                  \
                if (_c >= 2) tab16[2 * tpad + _c - 2] = _v;                  \
                if (_c >= 3) tab16[3 * tpad + _c - 3] = _v;                  \
            } else {                                                         \
                uint32_t _v = (uint32_t)(pf) | ((uint32_t)(kf) << 16);       \
                tab32[_c] = _v;                                              \
                if (_c >= 1) tab32[tpad     + _c - 1] = _v;                  \
                if (_c >= 2) tab32[2 * tpad + _c - 2] = _v;                  \
                if (_c >= 3) tab32[3 * tpad + _c - 3] = _v;                  \
            }                                                                \
        } while (0)

        if (p < m) WR4(p, P, p);                  // order-1
        WR4(m + p, p, m);                         // order-2

        int mi = m - i;
        long long Si  = ((long long)m * (m + 1) * (m + 2)
                       - (long long)mi * (mi + 1) * (mi + 2)) / 6;
        int Rij = ((m - i) + (m - j + 1)) * (j - i) / 2;
        int base = m + P + (int)Si + Rij;
        for (int k3 = j; k3 < m; ++k3)
            WR4(base + (k3 - j), p, k3);
        #undef WR4
    }
}

// ---------------------------------------------------------------------------
// xsel[row*XW + k] = x[row*80 + idx[k]] for k<m, 1.0 for k>=m (sentinel).
// ---------------------------------------------------------------------------
__global__ void maskde_xsel(const float* __restrict__ x,
                            const int* __restrict__ idx,
                            float* __restrict__ xsel, int m, int rows) {
    int g = blockIdx.x * BLK + threadIdx.x;
    int total = rows * XW;
    for (; g < total; g += gridDim.x * BLK) {
        int row = g / XW, k = g - row * XW;
        xsel[g] = (k < m) ? x[row * DMAX + idx[k]] : 1.0f;
    }
}

// ---------------------------------------------------------------------------
// Expand, fill-shaped: block b writes flat [b*epb, (b+1)*epb) -- consecutive
// blocks = consecutive bytes.  Stages <=NR rows' xls+pps in LDS once, then
// iterates row segments; within a segment the alignment phase is constant,
// the hot loop is: 1 aligned uint2/uint4 table load (L2) + 8 LDS reads +
// 4 muls + 1 aligned float4 store.  No per-quad branches.
// ---------------------------------------------------------------------------
template<bool U16>
__global__ __launch_bounds__(BLK) void
maskde_expand(const float* __restrict__ xsel,
              const uint16_t* __restrict__ pair16,
              const uint16_t* __restrict__ tab16,
              const uint32_t* __restrict__ tab32,
              int tpad, float* __restrict__ out,
              int m, int T, int P, int rows, int epb, int total) {
    extern __shared__ float sm[];
    const int PPS = P + 1;
    float* xls = sm;             // NR * XL
    float* pps = sm + NR * XL;   // NR * PPS

    const int tid  = threadIdx.x;
    const int e0   = blockIdx.x * epb;
    const int eend = min(e0 + epb, total);
    const int r0   = e0 / T;

    // stage xls for up to NR rows (xsel has 1.0 sentinels at k>=m)
    for (int q = tid; q < NR * XL; q += BLK) {
        int rr = q >> 6, k = q & (XL - 1);
        int row = r0 + rr;
        xls[q] = (row < rows) ? xsel[row * XW + k] : 1.0f;
    }
    __syncthreads();

    // pair products per staged row (+ sentinel 1.0 at p=P)
    for (int rr = 0; rr < NR; ++rr) {
        int row = r0 + rr;
        if (row >= rows) break;
        const float* xr = xls + rr * XL;
        float*       pr = pps + rr * PPS;
        for (int p = tid; p <= P; p += BLK) {
            float v = 1.0f;
            if (p < P) {
                uint32_t ij = pair16[p];
                v = xr[ij & 0xFF] * xr[(ij >> 8) & 0xFF];
            }
            pr[p] = v;
        }
    }
    __syncthreads();

    // row segments
    int a = e0;
    for (int rr = 0; rr < NR && a < eend; ++rr) {
        const int row = r0 + rr;
        const long long rowend = (long long)(row + 1) * T;
        const int b = (int)(rowend < (long long)eend ? rowend : (long long)eend);
        const float* xr = xls + rr * XL;
        const float* pr = pps + rr * PPS;
        const int cbase = a - row * T;

        int ahead = a + ((4 - (a & 3)) & 3);
        if (ahead > b) ahead = b;

        // scalar head (<=3 elems, base table copy)
        if (tid < ahead - a) {
            int c = cbase + tid;
            uint32_t p_, k_;
            if constexpr (U16) { uint16_t t = tab16[c]; p_ = t & 0x3FF; k_ = t >> 10; }
            else               { uint32_t t = tab32[c]; p_ = t & 0xFFFF; k_ = t >> 16; }
            out[a + tid] = pr[p_] * xr[k_];
        }

        const int nq    = (b - ahead) >> 2;
        const int calig = cbase + (ahead - a);
        const int s4    = calig & 3;

        if constexpr (U16) {
            const uint16_t* tb = tab16 + (size_t)s4 * tpad + (calig - s4);
            for (int q = tid; q < nq; q += BLK) {
                uint2 t = *(const uint2*)(tb + 4 * q);   // 8B aligned
                f32x4 o;
                o.x = pr[t.x & 0x3FF]         * xr[(t.x >> 10) & 0x3F];
                o.y = pr[(t.x >> 16) & 0x3FF] * xr[t.x >> 26];
                o.z = pr[t.y & 0x3FF]         * xr[(t.y >> 10) & 0x3F];
                o.w = pr[(t.y >> 16) & 0x3FF] * xr[t.y >> 26];
                *(f32x4*)(out + ahead + 4 * q) = o;      // 16B aligned
            }
        } else {
            const uint32_t* tb = tab32 + (size_t)s4 * tpad + (calig - s4);
            for (int q = tid; q < nq; q += BLK) {
                uint4 t = *(const uint4*)(tb + 4 * q);   // 16B aligned
                f32x4 o;
                o.x = pr[t.x & 0xFFFF] * xr[t.x >> 16];
                o.y = pr[t.y & 0xFFFF] * xr[t.y >> 16];
                o.z = pr[t.z & 0xFFFF] * xr[t.z >> 16];
                o.w = pr[t.w & 0xFFFF] * xr[t.w >> 16];
                *(f32x4*)(out + ahead + 4 * q) = o;
            }
        }

        // scalar tail (<=3 elems, base table copy)
        const int ts = ahead + 4 * nq;
        if (tid < b - ts) {
            int c = cbase + (ts - a) + tid;
            uint32_t p_, k_;
            if constexpr (U16) { uint16_t t = tab16[c]; p_ = t & 0x3FF; k_ = t >> 10; }
            else               { uint32_t t = tab32[c]; p_ = t & 0xFFFF; k_ = t >> 16; }
            out[ts + tid] = pr[p_] * xr[k_];
        }
        a = b;
    }
}

extern "C" void kernel_launch(void* const* d_in, const int* in_sizes, int n_in,
                              void* d_out, int out_size, void* d_ws, size_t ws_size,
                              hipStream_t stream) {
    const float* x    = (const float*)d_in[0];
    const void*  mask = d_in[1];
    float*       out  = (float*)d_out;

    int rows = in_sizes[0] / DMAX;
    if (rows <= 0 || out_size <= 0) return;
    long long Tll = (long long)out_size / rows;

    // recover m from T(m) = m + m(m+1)/2 + m(m+1)(m+2)/6
    int m = -1;
    for (int mm = 0; mm <= DMAX; ++mm) {
        long long t = (long long)mm
                    + (long long)mm * (mm + 1) / 2
                    + (long long)mm * (mm + 1) * (mm + 2) / 6;
        if (t == Tll) { m = mm; break; }
    }
    if (m <= 0) return;

    int T     = (int)Tll;
    int P     = m * (m + 1) / 2;
    int tpad  = (T + 3) & ~3;
    int total = rows * T;
    int use16 = (P < 1024 && m < 63) ? 1 : 0;

    int epb = EPBMAX;
    if (epb > 2 * T) epb = T & ~3;        // keep rows-per-block <= NR
    if (epb < 4) epb = 4;

    // workspace layout (256B-aligned regions)
    char* ws = (char*)d_ws;
    int*      idx    = (int*)ws;                              // 512 B
    uint16_t* pair16 = (uint16_t*)(ws + 1024);                // 2P B
    uint16_t* tab16  = (uint16_t*)(ws + 32768);               // 4*tpad u16
    uint32_t* tab32  = (uint32_t*)(ws + 32768);               // 4*tpad u32 (aliased)
    size_t off_xsel  = 32768 + (size_t)4 * tpad * 4 + 256;
    off_xsel = (off_xsel + 255) & ~(size_t)255;
    float*    xsel   = (float*)(ws + off_xsel);               // rows*XW f32

    int sblocks = (P + 255) / 256;
    if (sblocks < 1) sblocks = 1;
    maskde_setup<<<sblocks, 256, 0, stream>>>(mask, m, idx, pair16, tab16,
                                              tab32, use16, tpad, T, P);

    int xblocks = (rows * XW + BLK - 1) / BLK;
    if (xblocks > 2048) xblocks = 2048;
    maskde_xsel<<<xblocks, BLK, 0, stream>>>(x, idx, xsel, m, rows);

    int nb = (total + epb - 1) / epb;
    size_t shmem = (size_t)(NR * XL + NR * (P + 1)) * sizeof(float);
    if (use16)
        maskde_expand<true><<<nb, BLK, shmem, stream>>>(xsel, pair16, tab16,
                                                        tab32, tpad, out, m, T,
                                                        P, rows, epb, total);
    else
        maskde_expand<false><<<nb, BLK, shmem, stream>>>(xsel, pair16, tab16,
                                                         tab32, tpad, out, m, T,
                                                         P, rows, epb, total);
}